// Round 5
// baseline (76.205 us; speedup 1.0000x reference)
//
#include <hip/hip_runtime.h>

constexpr int NCLS = 16;
constexpr int NG   = 50;
constexpr int CH   = 21;           // 5 + NCLS
constexpr int N0 = 16384, N1 = 4096, N2 = 1024;
constexpr int NTOT   = N0 + N1 + N2;   // 21504
constexpr int CHUNKS = NTOT / 256;     // 84 (each block fully inside one level)
constexpr float EPSF = 1e-8f;
constexpr int IMAX = 0x7fffffff;

// ws layout: ctr[i] at int offset i*16 (64B apart), i=0..7 first level,
// i=8 second level. Partials (float, SoA [5][nb]) start at float offset 256.
constexpr int CTR_STRIDE = 16;
constexpr int CTR2_IDX   = 8 * CTR_STRIDE;
constexpr int CTR_BYTES  = (8 * CTR_STRIDE + CTR_STRIDE) * 4;  // 576 B
constexpr int PART_OFF   = 256;

__global__ __launch_bounds__(256) void dpsv_fused_kernel(
    const float* __restrict__ in0,
    const float* __restrict__ in1,
    const float* __restrict__ in2,
    const float* __restrict__ labels,
    int*   __restrict__ ctrs,
    float* __restrict__ parts,
    float* __restrict__ out, int nb)
{
    const int tid   = threadIdx.x;
    const int b     = blockIdx.x / CHUNKS;
    const int chunk = blockIdx.x % CHUNKS;
    const int p     = chunk * 256 + tid;

    // ---- level decode (block-uniform) ----
    const float* basep; int hw, Wlog, HW; float s;
    if (p < N0)           { basep = in0; hw = p;           Wlog = 7; HW = N0; s = 8.f;  }
    else if (p < N0 + N1) { basep = in1; hw = p - N0;      Wlog = 6; HW = N1; s = 16.f; }
    else                  { basep = in2; hw = p - N0 - N1; Wlog = 5; HW = N2; s = 32.f; }
    const int x = hw & ((1 << Wlog) - 1);
    const int y = hw >> Wlog;
    const float fx = (float)x, fy = (float)y;
    const float cx = (fx + 0.5f) * s;
    const float cy = (fy + 0.5f) * s;
    const float r  = 0.5f * s;

    const float* ch = basep + (size_t)(b * CH) * HW + hw;
    const float obj = ch[4 * HW];        // issue early; latency hides under matching

    // ---- wave-local GT banding (no LDS, no syncs) ----
    const int lane = tid & 63;
    const int hwb  = hw - lane;          // wave's first anchor
    int xb_min, xb_max;
    if (Wlog >= 6) { xb_min = hwb & ((1 << Wlog) - 1); xb_max = xb_min + 63; }
    else           { xb_min = 0;         xb_max = (1 << Wlog) - 1; }
    const int yb_min = hwb >> Wlog;
    const int yb_max = (hwb + 63) >> Wlog;
    const float cxLo = ((float)xb_min + 0.5f) * s - r;
    const float cxHi = ((float)xb_max + 0.5f) * s + r;
    const float cyLo = ((float)yb_min + 0.5f) * s - r;
    const float cyHi = ((float)yb_max + 0.5f) * s + r;

    const float* labB = labels + b * 5 * NG;
    float gx = 0.f, gy = 0.f;
    bool band = false;
    if (lane < NG) {
        gx = labB[lane * 5 + 0];
        gy = labB[lane * 5 + 1];
        band = (gx > cxLo) && (gx < cxHi) && (gy > cyLo) && (gy < cyHi);
    }
    unsigned long long mask = __ballot(band);

    int matched = IMAX;
    while (mask) {                        // wave-uniform; usually zero iterations
        int j = __builtin_ctzll(mask);
        mask &= mask - 1;
        float gxj = __shfl(gx, j, 64);
        float gyj = __shfl(gy, j, 64);
        bool inr = (fabsf(cx - gxj) < r) && (fabsf(cy - gyj) < r);
        matched = min(matched, inr ? j : IMAX);
    }
    const bool fg = (matched != IMAX);

    // ---- obj term (all anchors) ----
    float loss_part = fg ? (-1000.f * __logf(obj + EPSF))
                         : (-__logf(1.f - obj + EPSF));
    float v0 = 0.f, v1 = 0.f, v2 = 0.f, v3 = 0.f;

    // ---- vec + cls terms (rare fg lanes; labels read direct from global) ----
    if (fg) {
        const float* lg = labB + matched * 5;
        float xp = (ch[0]  + fx) * s;
        float yp = (ch[HW] + fy) * s;
        v0 = fabsf((lg[0] - xp) * (1.f / 1024.f));
        v1 = fabsf((lg[1] - yp) * (1.f / 1024.f));
        v2 = fabsf(lg[2] - ch[2 * HW]) * 10.f;
        v3 = fabsf(lg[3] - ch[3 * HW]) * 10.f;
        int ci = (int)lg[4];
        float cls_sum = 0.f;
        #pragma unroll
        for (int c = 0; c < NCLS; ++c) {
            float pc  = ch[(5 + c) * HW];
            float lp  = fmaxf(__logf(pc), -100.f);
            float l1p = fmaxf(__logf(1.f - pc), -100.f);
            cls_sum += (c == ci) ? -lp : -l1p;
        }
        loss_part += 500.f * cls_sum;
    }

    // ---- block reduction: wave shuffle -> LDS tree ----
    float vals[5] = {loss_part, v0, v1, v2, v3};
    {
        float v = vals[0];
        #pragma unroll
        for (int off = 32; off > 0; off >>= 1)
            v += __shfl_xor(v, off, 64);
        vals[0] = v;
    }
    if (__ballot(fg) != 0ull) {
        #pragma unroll
        for (int k = 1; k < 5; ++k) {
            float v = vals[k];
            #pragma unroll
            for (int off = 32; off > 0; off >>= 1)
                v += __shfl_xor(v, off, 64);
            vals[k] = v;
        }
    }
    __shared__ float red[4][5];
    const int wave = tid >> 6;
    if (lane == 0) {
        #pragma unroll
        for (int k = 0; k < 5; ++k) red[wave][k] = vals[k];
    }
    __syncthreads();

    // ---- completion protocol: tid0 stores partials, fences, increments ----
    __shared__ int rank2;
    if (tid == 0) {
        #pragma unroll
        for (int k = 0; k < 5; ++k)
            parts[k * nb + blockIdx.x] =
                red[0][k] + red[1][k] + red[2][k] + red[3][k];
        __threadfence();                         // release partials device-wide
        const int cidx  = blockIdx.x & 7;
        const int quota = ((nb - 1 - cidx) >> 3) + 1;
        int r2 = -1;
        int old = atomicAdd(&ctrs[cidx * CTR_STRIDE], 1);
        if (old == quota - 1)                    // last block of this group
            r2 = atomicAdd(&ctrs[CTR2_IDX], 1);
        rank2 = r2;
    }
    __syncthreads();

    // ---- THE final block: reduce all partials and write the output ----
    if (rank2 == 7) {
        __threadfence();                         // acquire
        float acc[5] = {0.f, 0.f, 0.f, 0.f, 0.f};
        for (int i = tid; i < nb; i += 256) {
            #pragma unroll
            for (int k = 0; k < 5; ++k) acc[k] += parts[k * nb + i];
        }
        #pragma unroll
        for (int k = 0; k < 5; ++k) {
            float v = acc[k];
            #pragma unroll
            for (int off = 32; off > 0; off >>= 1)
                v += __shfl_xor(v, off, 64);
            acc[k] = v;
        }
        if (lane == 0) {
            #pragma unroll
            for (int k = 0; k < 5; ++k) red[wave][k] = acc[k];
        }
        __syncthreads();
        if (tid == 0) {
            float t[5];
            #pragma unroll
            for (int k = 0; k < 5; ++k)
                t[k] = red[0][k] + red[1][k] + red[2][k] + red[3][k];
            out[0] = t[0] + 10000.f * (t[1] + t[2] + t[3] + t[4]);
            out[1] = t[1];
            out[2] = t[2];
            out[3] = t[3];
            out[4] = t[4];
        }
    }
}

extern "C" void kernel_launch(void* const* d_in, const int* in_sizes, int n_in,
                              void* d_out, int out_size, void* d_ws, size_t ws_size,
                              hipStream_t stream) {
    const float* in0    = (const float*)d_in[0];
    const float* in1    = (const float*)d_in[1];
    const float* in2    = (const float*)d_in[2];
    const float* labels = (const float*)d_in[3];
    float* out   = (float*)d_out;
    int*   ctrs  = (int*)d_ws;
    float* parts = (float*)d_ws + PART_OFF;

    const int B  = in_sizes[3] / (5 * NG);   // 32
    const int nb = B * CHUNKS;               // 2688

    // zero the completion counters each call (ws is poisoned once, never restored)
    hipMemsetAsync(d_ws, 0, CTR_BYTES, stream);

    dpsv_fused_kernel<<<nb, 256, 0, stream>>>(in0, in1, in2, labels,
                                              ctrs, parts, out, nb);
}

// Round 6
// 20.365 us; speedup vs baseline: 3.7419x; 3.7419x over previous
//
#include <hip/hip_runtime.h>

constexpr int NCLS = 16;
constexpr int NG   = 50;
constexpr int CH   = 21;           // 5 + NCLS
constexpr int N0 = 16384, N1 = 4096, N2 = 1024;
constexpr int NTOT   = N0 + N1 + N2;   // 21504
constexpr int CHUNKS = NTOT / 256;     // 84 (each 256-anchor chunk inside one level)
constexpr int IPB    = 2;              // items (chunks) per block
constexpr float EPSF = 1e-8f;
constexpr int IMAX = 0x7fffffff;

// Per-(b,chunk-of-256) item: match + obj + rare fg epilogue, accumulated into vals[5].
__device__ __forceinline__ void process_item(
    int item, int grid_items_stride /*unused*/, 
    const float* __restrict__ in0, const float* __restrict__ in1,
    const float* __restrict__ in2, const float* __restrict__ labels,
    int tid, float vals[5])
{
    const int b     = item / CHUNKS;
    const int chunk = item % CHUNKS;
    const int p     = chunk * 256 + tid;

    // level decode (block-uniform)
    const float* basep; int hw, Wlog, HW; float s;
    if (p < N0)           { basep = in0; hw = p;           Wlog = 7; HW = N0; s = 8.f;  }
    else if (p < N0 + N1) { basep = in1; hw = p - N0;      Wlog = 6; HW = N1; s = 16.f; }
    else                  { basep = in2; hw = p - N0 - N1; Wlog = 5; HW = N2; s = 32.f; }
    const int x = hw & ((1 << Wlog) - 1);
    const int y = hw >> Wlog;
    const float fx = (float)x, fy = (float)y;
    const float cx = (fx + 0.5f) * s;
    const float cy = (fy + 0.5f) * s;
    const float r  = 0.5f * s;

    const float* ch = basep + (size_t)(b * CH) * HW + hw;
    const float obj = ch[4 * HW];          // issue early

    // wave-local GT banding (no LDS, no block sync)
    const int lane = tid & 63;
    const int hwb  = hw - lane;
    int xb_min, xb_max;
    if (Wlog >= 6) { xb_min = hwb & ((1 << Wlog) - 1); xb_max = xb_min + 63; }
    else           { xb_min = 0;         xb_max = (1 << Wlog) - 1; }
    const int yb_min = hwb >> Wlog;
    const int yb_max = (hwb + 63) >> Wlog;
    const float cxLo = ((float)xb_min + 0.5f) * s - r;
    const float cxHi = ((float)xb_max + 0.5f) * s + r;
    const float cyLo = ((float)yb_min + 0.5f) * s - r;
    const float cyHi = ((float)yb_max + 0.5f) * s + r;

    const float* labB = labels + b * 5 * NG;
    float gx = 0.f, gy = 0.f;
    bool band = false;
    if (lane < NG) {
        gx = labB[lane * 5 + 0];
        gy = labB[lane * 5 + 1];
        band = (gx > cxLo) && (gx < cxHi) && (gy > cyLo) && (gy < cyHi);
    }
    unsigned long long mask = __ballot(band);

    int matched = IMAX;
    while (mask) {                          // wave-uniform; usually zero iterations
        int j = __builtin_ctzll(mask);
        mask &= mask - 1;
        float gxj = __shfl(gx, j, 64);
        float gyj = __shfl(gy, j, 64);
        bool inr = (fabsf(cx - gxj) < r) && (fabsf(cy - gyj) < r);
        matched = min(matched, inr ? j : IMAX);
    }
    const bool fg = (matched != IMAX);

    vals[0] += fg ? (-1000.f * __logf(obj + EPSF))
                  : (-__logf(1.f - obj + EPSF));

    if (fg) {                               // ~0.7% of lanes
        const float* lg = labB + matched * 5;
        float xp = (ch[0]  + fx) * s;
        float yp = (ch[HW] + fy) * s;
        vals[1] += fabsf((lg[0] - xp) * (1.f / 1024.f));
        vals[2] += fabsf((lg[1] - yp) * (1.f / 1024.f));
        vals[3] += fabsf(lg[2] - ch[2 * HW]) * 10.f;
        vals[4] += fabsf(lg[3] - ch[3 * HW]) * 10.f;
        int ci = (int)lg[4];
        float cls_sum = 0.f;
        #pragma unroll
        for (int c = 0; c < NCLS; ++c) {
            float pc  = ch[(5 + c) * HW];
            float lp  = fmaxf(__logf(pc), -100.f);
            float l1p = fmaxf(__logf(1.f - pc), -100.f);
            cls_sum += (c == ci) ? -lp : -l1p;
        }
        vals[0] += 500.f * cls_sum;
    }
}

__global__ __launch_bounds__(256) void dpsv_main_kernel(
    const float* __restrict__ in0,
    const float* __restrict__ in1,
    const float* __restrict__ in2,
    const float* __restrict__ labels,
    float* __restrict__ ws, int nbp)
{
    const int tid = threadIdx.x;
    float vals[5] = {0.f, 0.f, 0.f, 0.f, 0.f};

    // IPB independent items -> ILP on the long-latency load chains;
    // the reduction below runs ONCE per block instead of once per item.
    #pragma unroll
    for (int it = 0; it < IPB; ++it)
        process_item(blockIdx.x + it * nbp, nbp, in0, in1, in2, labels, tid, vals);

    // block reduction: wave shuffle -> LDS -> per-block partial store (SoA)
    #pragma unroll
    for (int k = 0; k < 5; ++k) {
        float v = vals[k];
        #pragma unroll
        for (int off = 32; off > 0; off >>= 1)
            v += __shfl_xor(v, off, 64);
        vals[k] = v;
    }
    __shared__ float red[4][5];
    const int wave = tid >> 6;
    const int lane = tid & 63;
    if (lane == 0) {
        #pragma unroll
        for (int k = 0; k < 5; ++k) red[wave][k] = vals[k];
    }
    __syncthreads();
    if (tid < 5) {
        ws[tid * nbp + blockIdx.x] =
            red[0][tid] + red[1][tid] + red[2][tid] + red[3][tid];
    }
}

__global__ __launch_bounds__(256) void dpsv_reduce_kernel(
    const float* __restrict__ ws, float* __restrict__ out, int nbp)
{
    const int tid = threadIdx.x;
    float acc[5] = {0.f, 0.f, 0.f, 0.f, 0.f};
    for (int i = tid; i < nbp; i += 256) {
        #pragma unroll
        for (int k = 0; k < 5; ++k) acc[k] += ws[k * nbp + i];
    }
    #pragma unroll
    for (int k = 0; k < 5; ++k) {
        float v = acc[k];
        #pragma unroll
        for (int off = 32; off > 0; off >>= 1)
            v += __shfl_xor(v, off, 64);
        acc[k] = v;
    }
    __shared__ float red[4][5];
    const int wave = tid >> 6;
    const int lane = tid & 63;
    if (lane == 0) {
        #pragma unroll
        for (int k = 0; k < 5; ++k) red[wave][k] = acc[k];
    }
    __syncthreads();
    if (tid == 0) {
        float t[5];
        #pragma unroll
        for (int k = 0; k < 5; ++k)
            t[k] = red[0][k] + red[1][k] + red[2][k] + red[3][k];
        out[0] = t[0] + 10000.f * (t[1] + t[2] + t[3] + t[4]);
        out[1] = t[1];
        out[2] = t[2];
        out[3] = t[3];
        out[4] = t[4];
    }
}

extern "C" void kernel_launch(void* const* d_in, const int* in_sizes, int n_in,
                              void* d_out, int out_size, void* d_ws, size_t ws_size,
                              hipStream_t stream) {
    const float* in0    = (const float*)d_in[0];
    const float* in1    = (const float*)d_in[1];
    const float* in2    = (const float*)d_in[2];
    const float* labels = (const float*)d_in[3];
    float* out = (float*)d_out;
    float* ws  = (float*)d_ws;

    const int B   = in_sizes[3] / (5 * NG);  // 32
    const int nb  = B * CHUNKS;              // 2688 items
    const int nbp = nb / IPB;                // 1344 blocks, all resident (5.25/CU)

    dpsv_main_kernel<<<nbp, 256, 0, stream>>>(in0, in1, in2, labels, ws, nbp);
    dpsv_reduce_kernel<<<1, 256, 0, stream>>>(ws, out, nbp);
}

// Round 7
// 19.556 us; speedup vs baseline: 3.8968x; 1.0414x over previous
//
#include <hip/hip_runtime.h>

constexpr int NCLS = 16;
constexpr int NG   = 50;
constexpr int CH   = 21;                 // 5 + NCLS
constexpr float EPSF = 1e-8f;

// ws layout (floats): parts_bg[B*21] at 0; parts_fg[5][B] at B*21.
// All slots written unconditionally every call -> no memset needed.

// ---------------- bg: sum of -log(1-obj+eps) over ALL anchors ----------------
// grid = B*21 blocks: per batch, 16 blocks cover level0's obj plane (4096 f4),
// 4 blocks level1 (1024 f4), 1 block level2 (256 f4). One float4 per thread.
__global__ __launch_bounds__(256) void dpsv_bg_kernel(
    const float* __restrict__ in0, const float* __restrict__ in1,
    const float* __restrict__ in2, float* __restrict__ parts_bg)
{
    const int tid = threadIdx.x;
    const int b   = blockIdx.x / 21;
    const int r   = blockIdx.x % 21;

    const float* ptr;
    if (r < 16)      ptr = in0 + ((size_t)(b * CH + 4)) * 16384 + (size_t)(r * 256 + tid) * 4;
    else if (r < 20) ptr = in1 + ((size_t)(b * CH + 4)) * 4096  + (size_t)((r - 16) * 256 + tid) * 4;
    else             ptr = in2 + ((size_t)(b * CH + 4)) * 1024  + (size_t)tid * 4;

    const float4 o = *(const float4*)ptr;
    float v = -(__logf(1.f - o.x + EPSF) + __logf(1.f - o.y + EPSF) +
                __logf(1.f - o.z + EPSF) + __logf(1.f - o.w + EPSF));

    #pragma unroll
    for (int off = 32; off > 0; off >>= 1)
        v += __shfl_xor(v, off, 64);

    __shared__ float red[4];
    const int wave = tid >> 6;
    if ((tid & 63) == 0) red[wave] = v;
    __syncthreads();
    if (tid == 0)
        parts_bg[blockIdx.x] = red[0] + red[1] + red[2] + red[3];
}

// ---------------- fg: GT-centric candidates + corrections ----------------
// grid = B blocks. threads 0..149 map to (level, g). Each GT covers at most one
// anchor per level (r = s/2 => open unit interval in grid coords).
__global__ __launch_bounds__(256) void dpsv_fg_kernel(
    const float* __restrict__ in0, const float* __restrict__ in1,
    const float* __restrict__ in2, const float* __restrict__ labels,
    float* __restrict__ parts_fg, int B)
{
    const int tid = threadIdx.x;
    const int b   = blockIdx.x;

    __shared__ float lab[5 * NG];
    __shared__ int   cand[3 * NG];
    if (tid < 5 * NG) lab[tid] = labels[b * 5 * NG + tid];
    if (tid < 3 * NG) cand[tid] = -1;
    __syncthreads();

    const int lv = tid / NG;            // 0..2 for tid<150
    const int g  = tid % NG;

    int xm = -1, ym = -1, found = -1;
    float s = 0.f; int W = 0, HW = 0;
    if (tid < 150) {
        s = (float)(8 << lv);
        const float rr = 0.5f * s;
        W = 128 >> lv; HW = W * W;
        const float gx = lab[g * 5 + 0];
        const float gy = lab[g * 5 + 1];
        const int x0 = (int)floorf(gx / s);
        const int y0 = (int)floorf(gy / s);
        #pragma unroll
        for (int d = -1; d <= 1; ++d) {
            int xc = x0 + d;
            if (xc >= 0 && xc < W) {
                float cxc = ((float)xc + 0.5f) * s;
                if (cxc - (gx - rr) > 0.f && gx + rr - cxc > 0.f) xm = xc;
            }
            int yc = y0 + d;
            if (yc >= 0 && yc < W) {
                float cyc = ((float)yc + 0.5f) * s;
                if (cyc - (gy - rr) > 0.f && gy + rr - cyc > 0.f) ym = yc;
            }
        }
        if (xm >= 0 && ym >= 0) { found = ym * W + xm; cand[tid] = found; }
    }
    __syncthreads();

    // dedup: anchor matches the LOWEST GT index covering it (reference argmax-first)
    bool fg = (found >= 0);
    if (fg) {
        const int base = lv * NG;
        for (int gp = 0; gp < g; ++gp)
            if (cand[base + gp] == found) { fg = false; break; }
    }

    float vals[5] = {0.f, 0.f, 0.f, 0.f, 0.f};
    if (fg) {
        const float* inp = (lv == 0) ? in0 : (lv == 1) ? in1 : in2;
        const float* chp = inp + ((size_t)b * CH) * HW + found;
        const float obj = chp[4 * HW];
        // correction: replace bg term with fg obj term
        vals[0] = -1000.f * __logf(obj + EPSF) + __logf(1.f - obj + EPSF);
        float xp = (chp[0]      + (float)xm) * s;
        float yp = (chp[HW]     + (float)ym) * s;
        vals[1] = fabsf((lab[g * 5 + 0] - xp) * (1.f / 1024.f));
        vals[2] = fabsf((lab[g * 5 + 1] - yp) * (1.f / 1024.f));
        vals[3] = fabsf(lab[g * 5 + 2] - chp[2 * HW]) * 10.f;
        vals[4] = fabsf(lab[g * 5 + 3] - chp[3 * HW]) * 10.f;
        const int ci = (int)lab[g * 5 + 4];
        float cls_sum = 0.f;
        #pragma unroll
        for (int c = 0; c < NCLS; ++c) {
            float pc  = chp[(5 + c) * HW];
            float lp  = fmaxf(__logf(pc), -100.f);
            float l1p = fmaxf(__logf(1.f - pc), -100.f);
            cls_sum += (c == ci) ? -lp : -l1p;
        }
        vals[0] += 500.f * cls_sum;
    }

    // block reduce 5 values
    #pragma unroll
    for (int k = 0; k < 5; ++k) {
        float v = vals[k];
        #pragma unroll
        for (int off = 32; off > 0; off >>= 1)
            v += __shfl_xor(v, off, 64);
        vals[k] = v;
    }
    __shared__ float red[4][5];
    const int wave = tid >> 6;
    if ((tid & 63) == 0) {
        #pragma unroll
        for (int k = 0; k < 5; ++k) red[wave][k] = vals[k];
    }
    __syncthreads();
    if (tid < 5)
        parts_fg[tid * B + b] = red[0][tid] + red[1][tid] + red[2][tid] + red[3][tid];
}

// ---------------- final reduce ----------------
__global__ __launch_bounds__(256) void dpsv_reduce_kernel(
    const float* __restrict__ parts_bg, const float* __restrict__ parts_fg,
    float* __restrict__ out, int nbg, int B)
{
    const int tid = threadIdx.x;
    float acc[5] = {0.f, 0.f, 0.f, 0.f, 0.f};
    for (int i = tid; i < nbg; i += 256) acc[0] += parts_bg[i];
    for (int i = tid; i < B;   i += 256) {
        #pragma unroll
        for (int k = 0; k < 5; ++k) acc[k] += parts_fg[k * B + i];
    }
    #pragma unroll
    for (int k = 0; k < 5; ++k) {
        float v = acc[k];
        #pragma unroll
        for (int off = 32; off > 0; off >>= 1)
            v += __shfl_xor(v, off, 64);
        acc[k] = v;
    }
    __shared__ float red[4][5];
    const int wave = tid >> 6;
    if ((tid & 63) == 0) {
        #pragma unroll
        for (int k = 0; k < 5; ++k) red[wave][k] = acc[k];
    }
    __syncthreads();
    if (tid == 0) {
        float t[5];
        #pragma unroll
        for (int k = 0; k < 5; ++k)
            t[k] = red[0][k] + red[1][k] + red[2][k] + red[3][k];
        out[0] = t[0] + 10000.f * (t[1] + t[2] + t[3] + t[4]);
        out[1] = t[1];
        out[2] = t[2];
        out[3] = t[3];
        out[4] = t[4];
    }
}

extern "C" void kernel_launch(void* const* d_in, const int* in_sizes, int n_in,
                              void* d_out, int out_size, void* d_ws, size_t ws_size,
                              hipStream_t stream) {
    const float* in0    = (const float*)d_in[0];
    const float* in1    = (const float*)d_in[1];
    const float* in2    = (const float*)d_in[2];
    const float* labels = (const float*)d_in[3];
    float* out = (float*)d_out;
    float* ws  = (float*)d_ws;

    const int B   = in_sizes[3] / (5 * NG);  // 32
    const int nbg = B * 21;                  // 672 bg partials
    float* parts_bg = ws;
    float* parts_fg = ws + nbg;              // 5*B floats

    dpsv_bg_kernel<<<nbg, 256, 0, stream>>>(in0, in1, in2, parts_bg);
    dpsv_fg_kernel<<<B, 256, 0, stream>>>(in0, in1, in2, labels, parts_fg, B);
    dpsv_reduce_kernel<<<1, 256, 0, stream>>>(parts_bg, parts_fg, out, nbg, B);
}

// Round 8
// 16.332 us; speedup vs baseline: 4.6660x; 1.1974x over previous
//
#include <hip/hip_runtime.h>

constexpr int NCLS = 16;
constexpr int NG   = 50;
constexpr int CH   = 21;                 // 5 + NCLS
constexpr float EPSF = 1e-8f;

// ws layout (floats): parts_bg[B*21] at 0; parts_fg[5][B] at B*21.
// All slots written unconditionally every call -> no memset needed.

// ---------------- fused bg + fg ----------------
// grid = B*21 + B blocks.
//   blocks [0, B*21): bg — sum of -log(1-obj+eps) over all anchors' obj plane.
//   blocks [B*21, B*21+B): fg — GT-centric candidates + fg corrections (1 block/batch).
__global__ __launch_bounds__(256) void dpsv_fused_kernel(
    const float* __restrict__ in0, const float* __restrict__ in1,
    const float* __restrict__ in2, const float* __restrict__ labels,
    float* __restrict__ parts_bg, float* __restrict__ parts_fg, int B)
{
    const int tid = threadIdx.x;
    const int nbg = B * 21;

    if (blockIdx.x < (unsigned)nbg) {
        // ======== bg part: one float4 of the obj plane per thread ========
        const int b = blockIdx.x / 21;
        const int r = blockIdx.x % 21;

        const float* ptr;
        if (r < 16)      ptr = in0 + ((size_t)(b * CH + 4)) * 16384 + (size_t)(r * 256 + tid) * 4;
        else if (r < 20) ptr = in1 + ((size_t)(b * CH + 4)) * 4096  + (size_t)((r - 16) * 256 + tid) * 4;
        else             ptr = in2 + ((size_t)(b * CH + 4)) * 1024  + (size_t)tid * 4;

        const float4 o = *(const float4*)ptr;
        float v = -(__logf(1.f - o.x + EPSF) + __logf(1.f - o.y + EPSF) +
                    __logf(1.f - o.z + EPSF) + __logf(1.f - o.w + EPSF));

        #pragma unroll
        for (int off = 32; off > 0; off >>= 1)
            v += __shfl_xor(v, off, 64);

        __shared__ float redb[4];
        const int wave = tid >> 6;
        if ((tid & 63) == 0) redb[wave] = v;
        __syncthreads();
        if (tid == 0)
            parts_bg[blockIdx.x] = redb[0] + redb[1] + redb[2] + redb[3];
        return;
    }

    // ======== fg part: threads 0..149 map to (level, g) ========
    const int b = blockIdx.x - nbg;

    __shared__ float lab[5 * NG];
    __shared__ int   cand[3 * NG];
    if (tid < 5 * NG) lab[tid] = labels[b * 5 * NG + tid];
    if (tid < 3 * NG) cand[tid] = -1;
    __syncthreads();

    const int lv = tid / NG;            // 0..2 for tid<150
    const int g  = tid % NG;

    int xm = -1, ym = -1, found = -1;
    float s = 0.f; int W = 0, HW = 0;
    if (tid < 150) {
        s = (float)(8 << lv);
        const float rr = 0.5f * s;
        W = 128 >> lv; HW = W * W;
        const float gx = lab[g * 5 + 0];
        const float gy = lab[g * 5 + 1];
        const int x0 = (int)floorf(gx / s);
        const int y0 = (int)floorf(gy / s);
        #pragma unroll
        for (int d = -1; d <= 1; ++d) {
            int xc = x0 + d;
            if (xc >= 0 && xc < W) {
                float cxc = ((float)xc + 0.5f) * s;
                if (cxc - (gx - rr) > 0.f && gx + rr - cxc > 0.f) xm = xc;
            }
            int yc = y0 + d;
            if (yc >= 0 && yc < W) {
                float cyc = ((float)yc + 0.5f) * s;
                if (cyc - (gy - rr) > 0.f && gy + rr - cyc > 0.f) ym = yc;
            }
        }
        if (xm >= 0 && ym >= 0) { found = ym * W + xm; cand[tid] = found; }
    }
    __syncthreads();

    // dedup: anchor matches the LOWEST GT index covering it (reference argmax-first)
    bool fg = (found >= 0);
    if (fg) {
        const int base = lv * NG;
        for (int gp = 0; gp < g; ++gp)
            if (cand[base + gp] == found) { fg = false; break; }
    }

    float vals[5] = {0.f, 0.f, 0.f, 0.f, 0.f};
    if (fg) {
        const float* inp = (lv == 0) ? in0 : (lv == 1) ? in1 : in2;
        const float* chp = inp + ((size_t)b * CH) * HW + found;
        const float obj = chp[4 * HW];
        // correction: replace bg term with fg obj term
        vals[0] = -1000.f * __logf(obj + EPSF) + __logf(1.f - obj + EPSF);
        float xp = (chp[0]  + (float)xm) * s;
        float yp = (chp[HW] + (float)ym) * s;
        vals[1] = fabsf((lab[g * 5 + 0] - xp) * (1.f / 1024.f));
        vals[2] = fabsf((lab[g * 5 + 1] - yp) * (1.f / 1024.f));
        vals[3] = fabsf(lab[g * 5 + 2] - chp[2 * HW]) * 10.f;
        vals[4] = fabsf(lab[g * 5 + 3] - chp[3 * HW]) * 10.f;
        const int ci = (int)lab[g * 5 + 4];
        float cls_sum = 0.f;
        #pragma unroll
        for (int c = 0; c < NCLS; ++c) {
            float pc  = chp[(5 + c) * HW];
            float lp  = fmaxf(__logf(pc), -100.f);
            float l1p = fmaxf(__logf(1.f - pc), -100.f);
            cls_sum += (c == ci) ? -lp : -l1p;
        }
        vals[0] += 500.f * cls_sum;
    }

    // block reduce 5 values
    #pragma unroll
    for (int k = 0; k < 5; ++k) {
        float v = vals[k];
        #pragma unroll
        for (int off = 32; off > 0; off >>= 1)
            v += __shfl_xor(v, off, 64);
        vals[k] = v;
    }
    __shared__ float red[4][5];
    const int wave = tid >> 6;
    if ((tid & 63) == 0) {
        #pragma unroll
        for (int k = 0; k < 5; ++k) red[wave][k] = vals[k];
    }
    __syncthreads();
    if (tid < 5)
        parts_fg[tid * B + b] = red[0][tid] + red[1][tid] + red[2][tid] + red[3][tid];
}

// ---------------- final reduce ----------------
__global__ __launch_bounds__(256) void dpsv_reduce_kernel(
    const float* __restrict__ parts_bg, const float* __restrict__ parts_fg,
    float* __restrict__ out, int nbg, int B)
{
    const int tid = threadIdx.x;
    float acc[5] = {0.f, 0.f, 0.f, 0.f, 0.f};
    for (int i = tid; i < nbg; i += 256) acc[0] += parts_bg[i];
    for (int i = tid; i < B;   i += 256) {
        #pragma unroll
        for (int k = 0; k < 5; ++k) acc[k] += parts_fg[k * B + i];
    }
    #pragma unroll
    for (int k = 0; k < 5; ++k) {
        float v = acc[k];
        #pragma unroll
        for (int off = 32; off > 0; off >>= 1)
            v += __shfl_xor(v, off, 64);
        acc[k] = v;
    }
    __shared__ float red[4][5];
    const int wave = tid >> 6;
    if ((tid & 63) == 0) {
        #pragma unroll
        for (int k = 0; k < 5; ++k) red[wave][k] = acc[k];
    }
    __syncthreads();
    if (tid == 0) {
        float t[5];
        #pragma unroll
        for (int k = 0; k < 5; ++k)
            t[k] = red[0][k] + red[1][k] + red[2][k] + red[3][k];
        out[0] = t[0] + 10000.f * (t[1] + t[2] + t[3] + t[4]);
        out[1] = t[1];
        out[2] = t[2];
        out[3] = t[3];
        out[4] = t[4];
    }
}

extern "C" void kernel_launch(void* const* d_in, const int* in_sizes, int n_in,
                              void* d_out, int out_size, void* d_ws, size_t ws_size,
                              hipStream_t stream) {
    const float* in0    = (const float*)d_in[0];
    const float* in1    = (const float*)d_in[1];
    const float* in2    = (const float*)d_in[2];
    const float* labels = (const float*)d_in[3];
    float* out = (float*)d_out;
    float* ws  = (float*)d_ws;

    const int B   = in_sizes[3] / (5 * NG);  // 32
    const int nbg = B * 21;                  // 672 bg partials
    float* parts_bg = ws;
    float* parts_fg = ws + nbg;              // 5*B floats

    dpsv_fused_kernel<<<nbg + B, 256, 0, stream>>>(in0, in1, in2, labels,
                                                   parts_bg, parts_fg, B);
    dpsv_reduce_kernel<<<1, 256, 0, stream>>>(parts_bg, parts_fg, out, nbg, B);
}